// Round 2
// baseline (309.846 us; speedup 1.0000x reference)
//
#include <hip/hip_runtime.h>

// Problem constants (match reference)
#define RREL 8
#define COUT 4
#define NEDGE 2000000
#define E4   (NEDGE / 4)              // 500,000 float4 per relation
#define N4   (RREL * E4)              // 4,000,000 float4 in edge_w
#define TOT4 (COUT * N4)              // 16,000,000 float4 in out
#define BLOCK 256
#define GRID  (TOT4 / BLOCK)          // 62,500, exact — no tail check

typedef float vfloat4 __attribute__((ext_vector_type(4)));

// ---------------------------------------------------------------------------
// R2: pure copy-with-scale structure. One thread per OUTPUT float4:
// 1 coalesced 16B load + 1 coalesced 16B store — exactly the float4-copy
// pattern measured at 6.29 TB/s on this chip (m13). The previous 1-load/
// 4-store fan-out (4 write streams 64 MB apart, all serialized behind one
// load) ran at ~2.4 TB/s and was insensitive to NT-vs-plain stores.
//
// Input re-read cost: edge_w is 64 MB and fits L3 (256 MB). Blocks are
// dispatched channel-major, so each 64 MB input pass is separated by only
// ~128 MB of L3 traffic — channels 1-3 should hit Infinity Cache, keeping
// HBM traffic at ~64 MB read + 256 MB write (floor ~51 us).
//
// Softmax (4x8, 128 B) is recomputed redundantly per block; block 0 also
// writes the Filter tuple element.
// ---------------------------------------------------------------------------
__global__ void __launch_bounds__(BLOCK)
gtconv_copy_kernel(const vfloat4* __restrict__ ew4,   // [R*E/4]
                   const float* __restrict__ weight,  // [C, R]
                   vfloat4* __restrict__ out4,        // [C, R*E/4]
                   float* __restrict__ filter_out) {  // [C, R] tuple elem 1
    __shared__ float sf[COUT * RREL];

    int t = threadIdx.x;
    if (t < COUT) {
        // Thread t computes softmax row t (8 elements) serially.
        float v[RREL];
        float m = -3.402823e38f;
        #pragma unroll
        for (int r = 0; r < RREL; ++r) {
            v[r] = weight[t * RREL + r];
            m = fmaxf(m, v[r]);
        }
        float s = 0.0f;
        #pragma unroll
        for (int r = 0; r < RREL; ++r) {
            v[r] = __expf(v[r] - m);
            s += v[r];
        }
        float inv = 1.0f / s;
        #pragma unroll
        for (int r = 0; r < RREL; ++r) {
            float f = v[r] * inv;
            sf[t * RREL + r] = f;
            if (blockIdx.x == 0) filter_out[t * RREL + r] = f;
        }
    }
    __syncthreads();

    unsigned gid = blockIdx.x * BLOCK + t;        // < TOT4 exactly (fits u32)
    unsigned c = gid / (unsigned)N4;              // channel   (magic-mul)
    unsigned in_idx = gid - c * (unsigned)N4;     // index into edge_w (float4)
    unsigned r = in_idx / (unsigned)E4;           // relation  (magic-mul)

    float f = sf[c * RREL + r];
    out4[gid] = ew4[in_idx] * f;
}

extern "C" void kernel_launch(void* const* d_in, const int* in_sizes, int n_in,
                              void* d_out, int out_size, void* d_ws, size_t ws_size,
                              hipStream_t stream) {
    const float* edge_w = (const float*)d_in[0];   // [R, E] f32
    const float* weight = (const float*)d_in[1];   // [C, R] f32
    float* out = (float*)d_out;                    // [C*R*E] out ++ [C*R] Filter

    float* filter_slot = out + (size_t)COUT * RREL * NEDGE;

    gtconv_copy_kernel<<<GRID, BLOCK, 0, stream>>>(
        (const vfloat4*)edge_w, weight, (vfloat4*)out, filter_slot);
}

// Round 3
// 295.810 us; speedup vs baseline: 1.0474x; 1.0474x over previous
//
#include <hip/hip_runtime.h>

// Problem constants (match reference)
#define RREL 8
#define COUT 4
#define NEDGE 2000000
#define E4   (NEDGE / 4)      // 500,000 float4 per relation
#define N4   (RREL * E4)      // 4,000,000 float4 total in edge_w
#define BLOCK 256
#define GRID  (N4 / BLOCK)    // 15625, exact — no tail check needed

// Native vector type — __builtin_nontemporal_* requires a true vector,
// not HIP's float4 class wrapper.
typedef float vfloat4 __attribute__((ext_vector_type(4)));

// ---------------------------------------------------------------------------
// R3 = restore R0 (best measured: 294.3 us). Session model (fit over R0-R2):
//   bench dur ~= poison fill (~160 us, harness) + output copy (~80 us,
//   harness) + kernel. Under that decomposition the kernel times were
//   R0 ~54 us, R1(plain stores) ~60 us, R2(pure-copy, 4x re-read) ~70 us.
// R0's structure is minimal-traffic (64 MB read once + 256 MB write once,
// floor ~51 us @ 6.3 TB/s) and measured closest to it.
//
// Structure: every block redundantly computes the 4x8 softmax from `weight`
// (128 B, L2-broadcast — cheap), then scales its slice of edge_w into the
// 4 output channels. Block 0 also writes the Filter tuple output.
// One thread per float4 of edge_w: 1 NT 16B load, 4 NT 16B stores.
// ---------------------------------------------------------------------------
__global__ void __launch_bounds__(BLOCK)
gtconv_fused_kernel(const vfloat4* __restrict__ ew4,
                    const float* __restrict__ weight,   // [C, R]
                    vfloat4* __restrict__ out4,         // [C, R*E/4]
                    float* __restrict__ filter_out) {   // [C, R] tuple elem 1
    __shared__ float sf[COUT * RREL];

    int t = threadIdx.x;
    if (t < COUT) {
        // Thread t computes softmax row t (8 elements) serially.
        float v[RREL];
        float m = -3.402823e38f;
        #pragma unroll
        for (int r = 0; r < RREL; ++r) {
            v[r] = weight[t * RREL + r];
            m = fmaxf(m, v[r]);
        }
        float s = 0.0f;
        #pragma unroll
        for (int r = 0; r < RREL; ++r) {
            v[r] = __expf(v[r] - m);
            s += v[r];
        }
        float inv = 1.0f / s;
        #pragma unroll
        for (int r = 0; r < RREL; ++r) {
            float f = v[r] * inv;
            sf[t * RREL + r] = f;
            if (blockIdx.x == 0) filter_out[t * RREL + r] = f;
        }
    }
    __syncthreads();

    int idx = blockIdx.x * BLOCK + t;     // < N4 exactly, no tail
    int r = idx / E4;                     // relation index (magic-mul)

    vfloat4 w = __builtin_nontemporal_load(&ew4[idx]);

    #pragma unroll
    for (int c = 0; c < COUT; ++c) {
        float f = sf[c * RREL + r];
        vfloat4 o = w * f;
        __builtin_nontemporal_store(o, &out4[(size_t)c * N4 + idx]);
    }
}

extern "C" void kernel_launch(void* const* d_in, const int* in_sizes, int n_in,
                              void* d_out, int out_size, void* d_ws, size_t ws_size,
                              hipStream_t stream) {
    const float* edge_w = (const float*)d_in[0];   // [R, E] f32
    const float* weight = (const float*)d_in[1];   // [C, R] f32
    float* out = (float*)d_out;                    // [C*R*E] out ++ [C*R] Filter

    float* filter_slot = out + (size_t)COUT * RREL * NEDGE;

    gtconv_fused_kernel<<<GRID, BLOCK, 0, stream>>>(
        (const vfloat4*)edge_w, weight, (vfloat4*)out, filter_slot);
}